// Round 15
// baseline (168.193 us; speedup 1.0000x reference)
//
#include <hip/hip_runtime.h>

// Problem dims (fixed by setup_inputs)
#define BATCH 4
#define HH 128
#define WW 128
#define CC 128
#define BIN 64
#define NPIX (BATCH * HH * WW)   // 65536

typedef short bf16x8 __attribute__((ext_vector_type(8)));
typedef float f32x4 __attribute__((ext_vector_type(4)));

// round-to-nearest-even bf16 bits of f
__device__ __forceinline__ unsigned bf_hi(float f) {
    unsigned u = __float_as_uint(f);
    return (u + 0x7fffu + ((u >> 16) & 1u)) >> 16;
}
// A-operand split: per c, k' slots [4c..4c+3] = [xh, xh, xl, xl]
__device__ __forceinline__ uint2 split_aa(float f) {
    unsigned hb = bf_hi(f);
    float lo = f - __uint_as_float(hb << 16);
    unsigned lb = bf_hi(lo);
    return make_uint2(hb | (hb << 16), lb | (lb << 16));
}
// B-operand split: per c, k' slots = [wh, wl, wh, wl] -> same uint twice
__device__ __forceinline__ unsigned split_b(float f) {
    unsigned hb = bf_hi(f);
    float lo = f - __uint_as_float(hb << 16);
    unsigned lb = bf_hi(lo);
    return hb | (lb << 16);
}

// ---------------------------------------------------------------------------
// Kernel 1: 1x1 conv == GEMM via split-bf16 MFMA.
// v14: X prefetch at DEPTH-2 (sets A/B, named scalars — NO arrays/lambdas,
// the round-4 depth-2 spilled via address-taken locals). X is streamed
// (64MB, HBM-miss ~900cyc) but was issued only ~480cyc ahead -> per-chunk
// stall. Depth-2 issues X ~2 phases (~1000cyc) ahead. W stays depth-1
// (64KB L2-hot, ~200cyc, covered). __launch_bounds__(256,2): budget 128,
// est ~80-100 VGPR -> <=128 HW tier -> 16 waves/CU; LDS 36.9KB x4 =
// 147KB -> 4 blocks/CU (grid 1024 = exactly 4/CU).
// Y[p][d] = sum_c X[p][c]*W[c][d], fp32 reproduced as (xh+xl)*(wh+wl),
// K'=512 (4 bf16 slots per c). 128px x 128d tile, K' chunked by 64 (16 c).
// ---------------------------------------------------------------------------
#define AROW 72   // shorts per LDS row (64 k' + 8 pad)

__global__ __launch_bounds__(256, 2)
void conv_mfma_kernel(const float* __restrict__ Xm, const float* __restrict__ Xr,
                      const float* __restrict__ Wm, const float* __restrict__ Wr,
                      float* __restrict__ Ym, float* __restrict__ Yr) {
    const float* __restrict__ X = blockIdx.y ? Xr : Xm;
    const float* __restrict__ W = blockIdx.y ? Wr : Wm;
    float* __restrict__ Y       = blockIdx.y ? Yr : Ym;

    __shared__ unsigned short AT[128 * AROW];   // [px][k'] 18 KB
    __shared__ unsigned short BT[128 * AROW];   // [d][k']  18 KB

    const int t  = threadIdx.x;
    const int wv = t >> 6;
    const int l  = t & 63;
    const int wm = (wv >> 1) * 64;   // wave's px-quadrant
    const int wn = (wv & 1) * 64;    // wave's d-quadrant
    const int lr = l & 15;
    const int lq = l >> 4;
    const int p_base = blockIdx.x * 128;

    const int px = t >> 1, ahalf = t & 1;   // A staging: 2 thr/px, 8 c each
    const int d  = t & 127, bq = t >> 7;    // B staging: 2 thr/d, 8 c each

    f32x4 acc[4][4] = {};

    const float* xbase = X + (size_t)(p_base + px) * CC + ahalf * 8;

// staging bodies as macros (textual expansion — no address-taken locals)
#define STAGE_A(X0, X1)                                                        \
    {                                                                          \
        unsigned short* arow = &AT[px * AROW + ahalf * 32];                    \
        uint2 a0 = split_aa((X0).x), a1 = split_aa((X0).y),                    \
              a2 = split_aa((X0).z), a3 = split_aa((X0).w);                    \
        *(uint4*)(arow)     = make_uint4(a0.x, a0.y, a1.x, a1.y);              \
        *(uint4*)(arow + 8) = make_uint4(a2.x, a2.y, a3.x, a3.y);              \
        uint2 b0 = split_aa((X1).x), b1 = split_aa((X1).y),                    \
              b2 = split_aa((X1).z), b3 = split_aa((X1).w);                    \
        *(uint4*)(arow + 16) = make_uint4(b0.x, b0.y, b1.x, b1.y);             \
        *(uint4*)(arow + 24) = make_uint4(b2.x, b2.y, b3.x, b3.y);             \
    }
#define STAGE_B()                                                              \
    {                                                                          \
        unsigned s0 = split_b(wb0), s1 = split_b(wb1),                         \
                 s2 = split_b(wb2), s3 = split_b(wb3);                         \
        unsigned short* brow = &BT[d * AROW + (bq * 2) * 16];                  \
        *(uint4*)(brow)     = make_uint4(s0, s0, s1, s1);                      \
        *(uint4*)(brow + 8) = make_uint4(s2, s2, s3, s3);                      \
        unsigned s4 = split_b(wb4), s5 = split_b(wb5),                         \
                 s6 = split_b(wb6), s7 = split_b(wb7);                         \
        unsigned short* brow2 = &BT[d * AROW + (bq * 2 + 1) * 16];             \
        *(uint4*)(brow2)     = make_uint4(s4, s4, s5, s5);                     \
        *(uint4*)(brow2 + 8) = make_uint4(s6, s6, s7, s7);                     \
    }
#define LOAD_W(KC)                                                             \
    {                                                                          \
        const float* wp0 = W + (size_t)((KC) + bq * 2 * 4) * CC + d;           \
        wb0 = wp0[0]; wb1 = wp0[CC]; wb2 = wp0[2 * CC]; wb3 = wp0[3 * CC];     \
        const float* wp1 = W + (size_t)((KC) + (bq * 2 + 1) * 4) * CC + d;     \
        wb4 = wp1[0]; wb5 = wp1[CC]; wb6 = wp1[2 * CC]; wb7 = wp1[3 * CC];     \
    }
#define MFMA_PHASE()                                                           \
    {                                                                          \
        _Pragma("unroll")                                                      \
        for (int ks = 0; ks < 2; ++ks) {                                       \
            bf16x8 af[4], bfr[4];                                              \
            _Pragma("unroll")                                                  \
            for (int mi = 0; mi < 4; ++mi)                                     \
                af[mi] = *(const bf16x8*)&AT[(wm + mi * 16 + lr) * AROW +      \
                                             ks * 32 + lq * 8];                \
            _Pragma("unroll")                                                  \
            for (int ni = 0; ni < 4; ++ni)                                     \
                bfr[ni] = *(const bf16x8*)&BT[(wn + ni * 16 + lr) * AROW +     \
                                              ks * 32 + lq * 8];               \
            _Pragma("unroll")                                                  \
            for (int mi = 0; mi < 4; ++mi)                                     \
                _Pragma("unroll")                                              \
                for (int ni = 0; ni < 4; ++ni)                                 \
                    acc[mi][ni] = __builtin_amdgcn_mfma_f32_16x16x32_bf16(     \
                        af[mi], bfr[ni], acc[mi][ni], 0, 0, 0);                \
        }                                                                      \
    }

    // ---- prologue: X chunks 0 (set A) and 1 (set B); W chunk 0 ----
    float4 xaA0 = *(const float4*)(xbase);
    float4 xaA1 = *(const float4*)(xbase + 4);
    float4 xaB0 = *(const float4*)(xbase + 16);
    float4 xaB1 = *(const float4*)(xbase + 20);
    float wb0, wb1, wb2, wb3, wb4, wb5, wb6, wb7;
    LOAD_W(0);

    for (int kc = 0; kc < CC; kc += 32) {
        // ---- chunk kc (X set A) ----
        __syncthreads();                    // prev MFMA reads done
        STAGE_A(xaA0, xaA1);
        STAGE_B();
        __syncthreads();
        if (kc + 32 < CC) {                 // X depth-2 prefetch
            const float* xp = xbase + kc + 32;
            xaA0 = *(const float4*)(xp);
            xaA1 = *(const float4*)(xp + 4);
        }
        LOAD_W(kc + 16);                    // W depth-1 (kc+16 <= 112 always)
        MFMA_PHASE();
        // ---- chunk kc+16 (X set B) ----
        __syncthreads();
        STAGE_A(xaB0, xaB1);
        STAGE_B();
        __syncthreads();
        if (kc + 48 < CC) {                 // X depth-2 prefetch
            const float* xp = xbase + kc + 48;
            xaB0 = *(const float4*)(xp);
            xaB1 = *(const float4*)(xp + 4);
        }
        if (kc + 32 < CC) LOAD_W(kc + 32);  // W depth-1
        MFMA_PHASE();
    }

    // epilogue: C/D layout col=lane&15, row=(lane>>4)*4+reg
#pragma unroll
    for (int mi = 0; mi < 4; ++mi)
#pragma unroll
        for (int ni = 0; ni < 4; ++ni)
#pragma unroll
            for (int reg = 0; reg < 4; ++reg) {
                const int row = p_base + wm + mi * 16 + lq * 4 + reg;
                Y[(size_t)row * CC + wn + ni * 16 + lr] = acc[mi][ni][reg];
            }
}

// ---------------------------------------------------------------------------
// Kernel 2: local 5x5 attention.  (v13 measured-best: 43.2us, VGPR 80,
// no spill, 4 blocks/CU phase mixing. UNCHANGED.)
// 8x8 tile, 256 thr (4 waves, 4 thr/px), grid 1024 = 4/CU.
// __launch_bounds__(256,2): budget 128, kernel needs ~80 (empirical rule:
// budget = 256/arg2 regardless of block size; (256,4) pinned 64 -> spill).
// GSLOT=157 (odd): 2512B group stride -> parts at distinct bank bases.
// OOB: staged addrs clamped; logits of invalid neighbors = 0; their
// softmax weights = 0 (exact zero-pad semantics).
// ---------------------------------------------------------------------------
#define TH 8
#define TW 8
#define HROW 13        // padded halo row width in float4 (12 real + 1 pad)
#define GSLOT 157      // 12*13=156 real slots + 1 (odd => bank skew)
#define NSLOT (8 * GSLOT)   // 1256 slots per buffer

__global__ __launch_bounds__(256, 2)
void attn_tile_kernel(const float* __restrict__ qm, const float* __restrict__ kr,
                      const float* __restrict__ vv, float* __restrict__ out) {
    __shared__ float4 KS[2][NSLOT];   // 40,192 B

    const int t    = threadIdx.x;
    const int wid  = t >> 6;          // 0..3
    const int ln   = t & 63;
    const int part = t & 3;           // channel-quarter owned by this lane
    const int pxi  = t >> 2;          // pixel 0..63 within tile

    const int bi = blockIdx.x >> 8;           // batch
    const int ty = (blockIdx.x >> 4) & 15;    // 16 tile-rows of 8
    const int tx = blockIdx.x & 15;           // 16 tile-cols of 8
    const int h0 = ty * TH, w0 = tx * TW;
    const int r = pxi >> 3, c = pxi & 7;
    const int h = h0 + r, w = w0 + c;
    const int gbase = bi * HH * WW;
    const int pix = gbase + h * WW + w;
    const int g0 = part * 2;                  // this lane's float4 groups

    // 25-bit validity mask for this pixel's window
    unsigned vm = 0;
#pragma unroll
    for (int dy = 0; dy < 5; ++dy)
#pragma unroll
        for (int dx = 0; dx < 5; ++dx) {
            const int hh = h + dy - 2, ww = w + dx - 2;
            if ((unsigned)hh < (unsigned)HH && (unsigned)ww < (unsigned)WW)
                vm |= 1u << (dy * 5 + dx);
        }

    // wave wid stages channel-groups {2wid, 2wid+1}; per group 3 DMA chunks
    // of 64 slots (last masked to 29 lanes). DMA dest = uniform base + ln*16.
    auto stage = [&](int p, int buf) {
        const float* src = (p < 4) ? kr : vv;
        const int ld = (p < 4) ? CC : BIN;
        const int chbase = (p < 4) ? p * 32 : (p - 4) * 32;
#pragma unroll
        for (int j = 0; j < 2; ++j) {
            const int g = wid * 2 + j;
            const int ch = chbase + g * 4;
#pragma unroll
            for (int i = 0; i < 3; ++i) {
                if (i < 2 || ln < GSLOT - 128) {
                    const int slot = i * 64 + ln;    // 0..156
                    const int py  = slot / 13;       // 0..12 (12 = pad row)
                    const int pxx = slot - py * 13;  // 0..12 (12 = pad col)
                    int hh = h0 + py - 2;  hh = hh < 0 ? 0 : (hh > HH - 1 ? HH - 1 : hh);
                    int ww = w0 + pxx - 2; ww = ww < 0 ? 0 : (ww > WW - 1 ? WW - 1 : ww);
                    const float* gp = src + (size_t)(gbase + hh * WW + ww) * ld + ch;
                    __builtin_amdgcn_global_load_lds(
                        (const __attribute__((address_space(1))) void*)gp,
                        (__attribute__((address_space(3))) void*)&KS[buf][g * GSLOT + i * 64],
                        16, 0, 0);
                }
            }
        }
    };

    float lg[25];
#pragma unroll
    for (int i = 0; i < 25; ++i) lg[i] = 0.0f;

    stage(0, 0);
    __syncthreads();

    for (int p = 0; p < 6; ++p) {
        if (p < 5) stage(p + 1, (p + 1) & 1);   // prefetch into other buffer
        const float4* B = KS[p & 1];
        if (p < 4) {
            // ---- logits chunk: 32 channels, this lane's 8 ----
            const float4* qp = (const float4*)(qm + (size_t)pix * CC + p * 32 + part * 8);
            float4 q0 = qp[0], q1 = qp[1];
#pragma unroll
            for (int dy = 0; dy < 5; ++dy)
#pragma unroll
                for (int dx = 0; dx < 5; ++dx) {
                    const int hp = (r + dy) * HROW + (c + dx);
                    float4 k0 = B[g0 * GSLOT + hp];
                    float4 k1 = B[g0 * GSLOT + GSLOT + hp];
                    lg[dy * 5 + dx] += q0.x * k0.x + q0.y * k0.y +
                                       q0.z * k0.z + q0.w * k0.w +
                                       q1.x * k1.x + q1.y * k1.y +
                                       q1.z * k1.z + q1.w * k1.w;
                }
        } else {
            if (p == 4) {
                // combine the 4 channel-quarters' partial logits
#pragma unroll
                for (int kk = 0; kk < 25; ++kk) {
                    float v = lg[kk];
                    v += __shfl_xor(v, 1);
                    v += __shfl_xor(v, 2);
                    lg[kk] = v;
                }
                // mask OOB logits to 0 (exact zero-pad semantics), softmax,
                // then zero the weights of OOB neighbors
#pragma unroll
                for (int kk = 0; kk < 25; ++kk)
                    if (!((vm >> kk) & 1)) lg[kk] = 0.0f;
                float mx = lg[0];
#pragma unroll
                for (int kk = 1; kk < 25; ++kk) mx = fmaxf(mx, lg[kk]);
                float sum = 0.0f;
#pragma unroll
                for (int kk = 0; kk < 25; ++kk) {
                    lg[kk] = __expf(lg[kk] - mx);
                    sum += lg[kk];
                }
                const float inv = 1.0f / sum;
#pragma unroll
                for (int kk = 0; kk < 25; ++kk)
                    lg[kk] = ((vm >> kk) & 1) ? lg[kk] * inv : 0.0f;
            }
            // ---- value-mix chunk: 32 bins, this lane's 8 ----
            float4 a0 = make_float4(0.f, 0.f, 0.f, 0.f);
            float4 a1 = make_float4(0.f, 0.f, 0.f, 0.f);
#pragma unroll
            for (int dy = 0; dy < 5; ++dy)
#pragma unroll
                for (int dx = 0; dx < 5; ++dx) {
                    const float wgt = lg[dy * 5 + dx];
                    const int hp = (r + dy) * HROW + (c + dx);
                    float4 v0 = B[g0 * GSLOT + hp];
                    float4 v1 = B[g0 * GSLOT + GSLOT + hp];
                    a0.x += wgt * v0.x; a0.y += wgt * v0.y;
                    a0.z += wgt * v0.z; a0.w += wgt * v0.w;
                    a1.x += wgt * v1.x; a1.y += wgt * v1.y;
                    a1.z += wgt * v1.z; a1.w += wgt * v1.w;
                }
            float4* op = (float4*)(out + (size_t)pix * BIN + (p - 4) * 32 + part * 8);
            op[0] = a0;
            op[1] = a1;
        }
        __syncthreads();
    }
}

extern "C" void kernel_launch(void* const* d_in, const int* in_sizes, int n_in,
                              void* d_out, int out_size, void* d_ws, size_t ws_size,
                              hipStream_t stream) {
    const float* main_in   = (const float*)d_in[0];
    const float* ref_in    = (const float*)d_in[1];
    const float* ref_value = (const float*)d_in[2];
    const float* W_main    = (const float*)d_in[3];
    const float* W_ref     = (const float*)d_in[4];
    float* out = (float*)d_out;

    float* conv_main = (float*)d_ws;                         // 32 MB
    float* conv_ref  = conv_main + (size_t)NPIX * CC;        // 32 MB

    dim3 gconv(NPIX / 128, 2);   // 1024 blocks = 4/CU
    conv_mfma_kernel<<<gconv, 256, 0, stream>>>(main_in, ref_in, W_main, W_ref,
                                                conv_main, conv_ref);

    // 1024 blocks = 4/CU: one 8x8 tile each, 4 threads per pixel
    attn_tile_kernel<<<1024, 256, 0, stream>>>(conv_main, conv_ref, ref_value, out);
}

// Round 16
// 166.096 us; speedup vs baseline: 1.0126x; 1.0126x over previous
//
#include <hip/hip_runtime.h>

// Problem dims (fixed by setup_inputs)
#define BATCH 4
#define HH 128
#define WW 128
#define CC 128
#define BIN 64
#define NPIX (BATCH * HH * WW)   // 65536

typedef short bf16x8 __attribute__((ext_vector_type(8)));
typedef float f32x4 __attribute__((ext_vector_type(4)));

// round-to-nearest-even bf16 bits of f
__device__ __forceinline__ unsigned bf_hi(float f) {
    unsigned u = __float_as_uint(f);
    return (u + 0x7fffu + ((u >> 16) & 1u)) >> 16;
}
// A-operand split: per c, k' slots [4c..4c+3] = [xh, xh, xl, xl]
__device__ __forceinline__ uint2 split_aa(float f) {
    unsigned hb = bf_hi(f);
    float lo = f - __uint_as_float(hb << 16);
    unsigned lb = bf_hi(lo);
    return make_uint2(hb | (hb << 16), lb | (lb << 16));
}
// B-operand split: per c, k' slots = [wh, wl, wh, wl] -> same uint twice
__device__ __forceinline__ unsigned split_b(float f) {
    unsigned hb = bf_hi(f);
    float lo = f - __uint_as_float(hb << 16);
    unsigned lb = bf_hi(lo);
    return hb | (lb << 16);
}

// ---------------------------------------------------------------------------
// Kernel 1: 1x1 conv == GEMM via split-bf16 MFMA.  (round-3 measured-best:
// depth-1 register prefetch, straight-line staging — no address-taken local
// arrays. Depth-2 at (256,2) [round 15] was neutral: +36 VGPR cost the
// waves doing the latency hiding (occupancy 17%). Reverted to the config
// of the 167.7us best total.)
// Y[p][d] = sum_c X[p][c]*W[c][d], fp32 reproduced as (xh+xl)*(wh+wl),
// K'=512 (4 bf16 slots per c). 128px x 128d tile, K' chunked by 64 (16 c).
// ---------------------------------------------------------------------------
#define AROW 72   // shorts per LDS row (64 k' + 8 pad)

__global__ __launch_bounds__(256, 4)
void conv_mfma_kernel(const float* __restrict__ Xm, const float* __restrict__ Xr,
                      const float* __restrict__ Wm, const float* __restrict__ Wr,
                      float* __restrict__ Ym, float* __restrict__ Yr) {
    const float* __restrict__ X = blockIdx.y ? Xr : Xm;
    const float* __restrict__ W = blockIdx.y ? Wr : Wm;
    float* __restrict__ Y       = blockIdx.y ? Yr : Ym;

    __shared__ unsigned short AT[128 * AROW];   // [px][k'] 18 KB
    __shared__ unsigned short BT[128 * AROW];   // [d][k']  18 KB

    const int t  = threadIdx.x;
    const int wv = t >> 6;
    const int l  = t & 63;
    const int wm = (wv >> 1) * 64;   // wave's px-quadrant
    const int wn = (wv & 1) * 64;    // wave's d-quadrant
    const int lr = l & 15;
    const int lq = l >> 4;
    const int p_base = blockIdx.x * 128;

    const int px = t >> 1, ahalf = t & 1;   // A staging: 2 thr/px, 8 c each
    const int d  = t & 127, bq = t >> 7;    // B staging: 2 thr/d, 8 c each

    f32x4 acc[4][4] = {};

    const float* xbase = X + (size_t)(p_base + px) * CC + ahalf * 8;

    // ---- prologue: prefetch chunk 0 into registers ----
    float4 xa0 = *(const float4*)(xbase);
    float4 xa1 = *(const float4*)(xbase + 4);
    float wb0, wb1, wb2, wb3, wb4, wb5, wb6, wb7;
    {
        const float* wp0 = W + (size_t)(bq * 2 * 4) * CC + d;
        wb0 = wp0[0]; wb1 = wp0[CC]; wb2 = wp0[2 * CC]; wb3 = wp0[3 * CC];
        const float* wp1 = W + (size_t)((bq * 2 + 1) * 4) * CC + d;
        wb4 = wp1[0]; wb5 = wp1[CC]; wb6 = wp1[2 * CC]; wb7 = wp1[3 * CC];
    }

    for (int kc = 0; kc < CC; kc += 16) {   // 16 c per chunk = 64 k'
        __syncthreads();                    // prev MFMA reads done
        // ---- stage A from regs (fp32 -> [h,h,l,l] bf16) ----
        {
            unsigned short* arow = &AT[px * AROW + ahalf * 32];
            {
                uint2 a0 = split_aa(xa0.x), a1 = split_aa(xa0.y),
                      a2 = split_aa(xa0.z), a3 = split_aa(xa0.w);
                *(uint4*)(arow)     = make_uint4(a0.x, a0.y, a1.x, a1.y);
                *(uint4*)(arow + 8) = make_uint4(a2.x, a2.y, a3.x, a3.y);
            }
            {
                uint2 a0 = split_aa(xa1.x), a1 = split_aa(xa1.y),
                      a2 = split_aa(xa1.z), a3 = split_aa(xa1.w);
                *(uint4*)(arow + 16) = make_uint4(a0.x, a0.y, a1.x, a1.y);
                *(uint4*)(arow + 24) = make_uint4(a2.x, a2.y, a3.x, a3.y);
            }
        }
        // ---- stage B from regs (fp32 -> [h,l,h,l] bf16, [d][k']) ----
        {
            unsigned b0 = split_b(wb0), b1 = split_b(wb1),
                     b2 = split_b(wb2), b3 = split_b(wb3);
            unsigned short* brow = &BT[d * AROW + (bq * 2) * 16];
            *(uint4*)(brow)     = make_uint4(b0, b0, b1, b1);
            *(uint4*)(brow + 8) = make_uint4(b2, b2, b3, b3);
            unsigned c0 = split_b(wb4), c1 = split_b(wb5),
                     c2 = split_b(wb6), c3 = split_b(wb7);
            unsigned short* brow2 = &BT[d * AROW + (bq * 2 + 1) * 16];
            *(uint4*)(brow2)     = make_uint4(c0, c0, c1, c1);
            *(uint4*)(brow2 + 8) = make_uint4(c2, c2, c3, c3);
        }
        __syncthreads();
        // ---- prefetch chunk kc+16 (overlaps MFMA below) ----
        if (kc + 16 < CC) {
            const float* xp = xbase + kc + 16;
            xa0 = *(const float4*)(xp);
            xa1 = *(const float4*)(xp + 4);
            const float* wp0 = W + (size_t)(kc + 16 + bq * 2 * 4) * CC + d;
            wb0 = wp0[0]; wb1 = wp0[CC]; wb2 = wp0[2 * CC]; wb3 = wp0[3 * CC];
            const float* wp1 = W + (size_t)(kc + 16 + (bq * 2 + 1) * 4) * CC + d;
            wb4 = wp1[0]; wb5 = wp1[CC]; wb6 = wp1[2 * CC]; wb7 = wp1[3 * CC];
        }
        // ---- MFMA: 2 k-steps of 32 ----
#pragma unroll
        for (int ks = 0; ks < 2; ++ks) {
            bf16x8 af[4], bfr[4];
#pragma unroll
            for (int mi = 0; mi < 4; ++mi)
                af[mi] = *(const bf16x8*)&AT[(wm + mi * 16 + lr) * AROW + ks * 32 + lq * 8];
#pragma unroll
            for (int ni = 0; ni < 4; ++ni)
                bfr[ni] = *(const bf16x8*)&BT[(wn + ni * 16 + lr) * AROW + ks * 32 + lq * 8];
#pragma unroll
            for (int mi = 0; mi < 4; ++mi)
#pragma unroll
                for (int ni = 0; ni < 4; ++ni)
                    acc[mi][ni] = __builtin_amdgcn_mfma_f32_16x16x32_bf16(
                        af[mi], bfr[ni], acc[mi][ni], 0, 0, 0);
        }
    }

    // epilogue: C/D layout col=lane&15, row=(lane>>4)*4+reg
#pragma unroll
    for (int mi = 0; mi < 4; ++mi)
#pragma unroll
        for (int ni = 0; ni < 4; ++ni)
#pragma unroll
            for (int reg = 0; reg < 4; ++reg) {
                const int row = p_base + wm + mi * 16 + lq * 4 + reg;
                Y[(size_t)row * CC + wn + ni * 16 + lr] = acc[mi][ni][reg];
            }
}

// ---------------------------------------------------------------------------
// Kernel 2: local 5x5 attention.  (v13 measured-best: 43.2us, VGPR 80,
// no spill, 4 blocks/CU phase mixing. UNCHANGED.)
// 8x8 tile, 256 thr (4 waves, 4 thr/px), grid 1024 = 4/CU.
// __launch_bounds__(256,2): budget 128, kernel needs ~80 (empirical rule:
// budget = 256/arg2 regardless of block size; (256,4) pinned 64 -> spill).
// GSLOT=157 (odd): 2512B group stride -> parts at distinct bank bases.
// OOB: staged addrs clamped; logits of invalid neighbors = 0; their
// softmax weights = 0 (exact zero-pad semantics).
// ---------------------------------------------------------------------------
#define TH 8
#define TW 8
#define HROW 13        // padded halo row width in float4 (12 real + 1 pad)
#define GSLOT 157      // 12*13=156 real slots + 1 (odd => bank skew)
#define NSLOT (8 * GSLOT)   // 1256 slots per buffer

__global__ __launch_bounds__(256, 2)
void attn_tile_kernel(const float* __restrict__ qm, const float* __restrict__ kr,
                      const float* __restrict__ vv, float* __restrict__ out) {
    __shared__ float4 KS[2][NSLOT];   // 40,192 B

    const int t    = threadIdx.x;
    const int wid  = t >> 6;          // 0..3
    const int ln   = t & 63;
    const int part = t & 3;           // channel-quarter owned by this lane
    const int pxi  = t >> 2;          // pixel 0..63 within tile

    const int bi = blockIdx.x >> 8;           // batch
    const int ty = (blockIdx.x >> 4) & 15;    // 16 tile-rows of 8
    const int tx = blockIdx.x & 15;           // 16 tile-cols of 8
    const int h0 = ty * TH, w0 = tx * TW;
    const int r = pxi >> 3, c = pxi & 7;
    const int h = h0 + r, w = w0 + c;
    const int gbase = bi * HH * WW;
    const int pix = gbase + h * WW + w;
    const int g0 = part * 2;                  // this lane's float4 groups

    // 25-bit validity mask for this pixel's window
    unsigned vm = 0;
#pragma unroll
    for (int dy = 0; dy < 5; ++dy)
#pragma unroll
        for (int dx = 0; dx < 5; ++dx) {
            const int hh = h + dy - 2, ww = w + dx - 2;
            if ((unsigned)hh < (unsigned)HH && (unsigned)ww < (unsigned)WW)
                vm |= 1u << (dy * 5 + dx);
        }

    // wave wid stages channel-groups {2wid, 2wid+1}; per group 3 DMA chunks
    // of 64 slots (last masked to 29 lanes). DMA dest = uniform base + ln*16.
    auto stage = [&](int p, int buf) {
        const float* src = (p < 4) ? kr : vv;
        const int ld = (p < 4) ? CC : BIN;
        const int chbase = (p < 4) ? p * 32 : (p - 4) * 32;
#pragma unroll
        for (int j = 0; j < 2; ++j) {
            const int g = wid * 2 + j;
            const int ch = chbase + g * 4;
#pragma unroll
            for (int i = 0; i < 3; ++i) {
                if (i < 2 || ln < GSLOT - 128) {
                    const int slot = i * 64 + ln;    // 0..156
                    const int py  = slot / 13;       // 0..12 (12 = pad row)
                    const int pxx = slot - py * 13;  // 0..12 (12 = pad col)
                    int hh = h0 + py - 2;  hh = hh < 0 ? 0 : (hh > HH - 1 ? HH - 1 : hh);
                    int ww = w0 + pxx - 2; ww = ww < 0 ? 0 : (ww > WW - 1 ? WW - 1 : ww);
                    const float* gp = src + (size_t)(gbase + hh * WW + ww) * ld + ch;
                    __builtin_amdgcn_global_load_lds(
                        (const __attribute__((address_space(1))) void*)gp,
                        (__attribute__((address_space(3))) void*)&KS[buf][g * GSLOT + i * 64],
                        16, 0, 0);
                }
            }
        }
    };

    float lg[25];
#pragma unroll
    for (int i = 0; i < 25; ++i) lg[i] = 0.0f;

    stage(0, 0);
    __syncthreads();

    for (int p = 0; p < 6; ++p) {
        if (p < 5) stage(p + 1, (p + 1) & 1);   // prefetch into other buffer
        const float4* B = KS[p & 1];
        if (p < 4) {
            // ---- logits chunk: 32 channels, this lane's 8 ----
            const float4* qp = (const float4*)(qm + (size_t)pix * CC + p * 32 + part * 8);
            float4 q0 = qp[0], q1 = qp[1];
#pragma unroll
            for (int dy = 0; dy < 5; ++dy)
#pragma unroll
                for (int dx = 0; dx < 5; ++dx) {
                    const int hp = (r + dy) * HROW + (c + dx);
                    float4 k0 = B[g0 * GSLOT + hp];
                    float4 k1 = B[g0 * GSLOT + GSLOT + hp];
                    lg[dy * 5 + dx] += q0.x * k0.x + q0.y * k0.y +
                                       q0.z * k0.z + q0.w * k0.w +
                                       q1.x * k1.x + q1.y * k1.y +
                                       q1.z * k1.z + q1.w * k1.w;
                }
        } else {
            if (p == 4) {
                // combine the 4 channel-quarters' partial logits
#pragma unroll
                for (int kk = 0; kk < 25; ++kk) {
                    float v = lg[kk];
                    v += __shfl_xor(v, 1);
                    v += __shfl_xor(v, 2);
                    lg[kk] = v;
                }
                // mask OOB logits to 0 (exact zero-pad semantics), softmax,
                // then zero the weights of OOB neighbors
#pragma unroll
                for (int kk = 0; kk < 25; ++kk)
                    if (!((vm >> kk) & 1)) lg[kk] = 0.0f;
                float mx = lg[0];
#pragma unroll
                for (int kk = 1; kk < 25; ++kk) mx = fmaxf(mx, lg[kk]);
                float sum = 0.0f;
#pragma unroll
                for (int kk = 0; kk < 25; ++kk) {
                    lg[kk] = __expf(lg[kk] - mx);
                    sum += lg[kk];
                }
                const float inv = 1.0f / sum;
#pragma unroll
                for (int kk = 0; kk < 25; ++kk)
                    lg[kk] = ((vm >> kk) & 1) ? lg[kk] * inv : 0.0f;
            }
            // ---- value-mix chunk: 32 bins, this lane's 8 ----
            float4 a0 = make_float4(0.f, 0.f, 0.f, 0.f);
            float4 a1 = make_float4(0.f, 0.f, 0.f, 0.f);
#pragma unroll
            for (int dy = 0; dy < 5; ++dy)
#pragma unroll
                for (int dx = 0; dx < 5; ++dx) {
                    const float wgt = lg[dy * 5 + dx];
                    const int hp = (r + dy) * HROW + (c + dx);
                    float4 v0 = B[g0 * GSLOT + hp];
                    float4 v1 = B[g0 * GSLOT + GSLOT + hp];
                    a0.x += wgt * v0.x; a0.y += wgt * v0.y;
                    a0.z += wgt * v0.z; a0.w += wgt * v0.w;
                    a1.x += wgt * v1.x; a1.y += wgt * v1.y;
                    a1.z += wgt * v1.z; a1.w += wgt * v1.w;
                }
            float4* op = (float4*)(out + (size_t)pix * BIN + (p - 4) * 32 + part * 8);
            op[0] = a0;
            op[1] = a1;
        }
        __syncthreads();
    }
}

extern "C" void kernel_launch(void* const* d_in, const int* in_sizes, int n_in,
                              void* d_out, int out_size, void* d_ws, size_t ws_size,
                              hipStream_t stream) {
    const float* main_in   = (const float*)d_in[0];
    const float* ref_in    = (const float*)d_in[1];
    const float* ref_value = (const float*)d_in[2];
    const float* W_main    = (const float*)d_in[3];
    const float* W_ref     = (const float*)d_in[4];
    float* out = (float*)d_out;

    float* conv_main = (float*)d_ws;                         // 32 MB
    float* conv_ref  = conv_main + (size_t)NPIX * CC;        // 32 MB

    dim3 gconv(NPIX / 128, 2);   // 1024 blocks = 4/CU
    conv_mfma_kernel<<<gconv, 256, 0, stream>>>(main_in, ref_in, W_main, W_ref,
                                                conv_main, conv_ref);

    // 1024 blocks = 4/CU: one 8x8 tile each, 4 threads per pixel
    attn_tile_kernel<<<1024, 256, 0, stream>>>(conv_main, conv_ref, ref_value, out);
}